// Round 9
// baseline (447.661 us; speedup 1.0000x reference)
//
#include <hip/hip_runtime.h>
#include <hip/hip_fp16.h>
#include <math.h>
#include <string.h>

// GAT 2-layer, N=100000, E=1600000, F_IN=128, HID=128 (H=4,C=32), OUT=64 (H=1,C=64)
// R8 -> R9: sort each dst's src-list ascending (in-LDS insertion sort inside
// bucket_sort). All concurrently-resident aggregate groups then read h rows
// from a sliding ~3MB window (k-th order statistic of uniform srcs), which
// fits the 4MB per-XCD L2 -> gather reuse becomes L2-hits. R7 proved footprint
// shrink alone doesn't help (hit rate capacity-insensitive); this shrinks the
// REUSE DISTANCE instead. Everything else unchanged from R8 (MFMA fp16 GEMMs
// with fused alphas, 4-node/wave aggregates).

#define BSH 9      // log2 dsts per bucket
#define DPB 512    // dsts per bucket
#define NBK 256    // max buckets (covers N < 131072)
#define CH1 16384  // edges per block in bucket_scatter
#define MAXB 12288 // LDS edge-buffer entries in bucket_sort (48 KB)
#define LOG2E 1.44269504088896f

using half8 = __attribute__((ext_vector_type(8))) _Float16;
using floatx4 = __attribute__((ext_vector_type(4))) float;

__device__ __forceinline__ float exp2_fast(float x) {
#if __has_builtin(__builtin_amdgcn_exp2f)
    return __builtin_amdgcn_exp2f(x);
#else
    return exp2f(x);
#endif
}

// ---------------- CSR build: bucketed counting sort ----------------

__global__ __launch_bounds__(256) void bucket_hist(const int* __restrict__ ei, int E, int N,
                                                   unsigned* __restrict__ bcount) {
    __shared__ unsigned hist[NBK];
    int t = threadIdx.x;
    hist[t] = 0;
    __syncthreads();
    int Etot = E + N;
    for (int k = blockIdx.x * 256 + t; k < Etot; k += gridDim.x * 256) {
        int d = (k < E) ? ei[E + k] : (k - E);
        atomicAdd(&hist[d >> BSH], 1u);
    }
    __syncthreads();
    unsigned c = hist[t];
    if (c) atomicAdd(&bcount[t], c);
}

__global__ void scan_buckets(const unsigned* __restrict__ bcount, unsigned* __restrict__ bbase,
                             unsigned* __restrict__ bcursor) {
    __shared__ unsigned s[NBK];
    int t = threadIdx.x;
    unsigned v = bcount[t];
    s[t] = v;
    __syncthreads();
    for (int o = 1; o < NBK; o <<= 1) {
        unsigned add = (t >= o) ? s[t - o] : 0;
        __syncthreads();
        s[t] += add;
        __syncthreads();
    }
    unsigned excl = s[t] - v;
    bbase[t] = excl;
    bcursor[t] = excl;
    if (t == NBK - 1) bbase[NBK] = excl + v;   // = Etot
}

// rec word: src in bits [0,17), dst low 9 bits in [17,26)
__global__ __launch_bounds__(256) void bucket_scatter(const int* __restrict__ ei, int E, int N,
                                                      unsigned* __restrict__ bcursor,
                                                      unsigned* __restrict__ rec) {
    __shared__ unsigned hist[NBK];
    __shared__ unsigned base[NBK];
    int t = threadIdx.x;
    hist[t] = 0;
    __syncthreads();
    int Etot = E + N;
    int k0 = blockIdx.x * CH1;
    int k1 = min(k0 + CH1, Etot);
    for (int k = k0 + t; k < k1; k += 256) {
        int d = (k < E) ? ei[E + k] : (k - E);
        atomicAdd(&hist[d >> BSH], 1u);
    }
    __syncthreads();
    unsigned c = hist[t];
    base[t] = c ? atomicAdd(&bcursor[t], c) : 0u;
    hist[t] = 0;
    __syncthreads();
    for (int k = k0 + t; k < k1; k += 256) {
        int s, d;
        if (k < E) { s = ei[k]; d = ei[E + k]; } else { s = d = k - E; }
        int b = d >> BSH;
        unsigned r = atomicAdd(&hist[b], 1u);
        rec[base[b] + r] = (unsigned)s | ((unsigned)(d & (DPB - 1)) << 17);
    }
}

// Counting-sort one 512-dst bucket; scatter into LDS, insertion-sort each
// dst's segment ascending by src, coalesced writeback.
__global__ __launch_bounds__(256) void bucket_sort(const unsigned* __restrict__ rec,
                                                   const unsigned* __restrict__ bbase,
                                                   int* __restrict__ offs, int* __restrict__ srcs,
                                                   int N, int Etot) {
    __shared__ unsigned hist[DPB];
    __shared__ unsigned tsum[256];
    __shared__ unsigned ebuf[MAXB];
    int t = threadIdx.x, bb = blockIdx.x;
    unsigned r0 = bbase[bb], r1 = bbase[bb + 1];
    unsigned cnt = r1 - r0;
    bool inLds = cnt <= MAXB;
    hist[t] = 0;
    hist[t + 256] = 0;
    __syncthreads();
    int dlo = bb << BSH;
    for (unsigned k = r0 + t; k < r1; k += 256) {
        unsigned e = rec[k];
        atomicAdd(&hist[e >> 17], 1u);
    }
    __syncthreads();
    unsigned h0 = hist[2 * t], h1 = hist[2 * t + 1];
    tsum[t] = h0 + h1;
    __syncthreads();
    for (int o = 1; o < 256; o <<= 1) {
        unsigned a = (t >= o) ? tsum[t - o] : 0;
        __syncthreads();
        tsum[t] += a;
        __syncthreads();
    }
    unsigned tb = tsum[t] - (h0 + h1);
    int d0 = dlo + 2 * t;
    if (d0 < N) offs[d0] = (int)(r0 + tb);
    if (d0 + 1 < N) offs[d0 + 1] = (int)(r0 + tb + h0);
    hist[2 * t] = tb;            // reuse as relative cursors
    hist[2 * t + 1] = tb + h0;
    __syncthreads();
    for (unsigned k = r0 + t; k < r1; k += 256) {
        unsigned e = rec[k];
        unsigned r = atomicAdd(&hist[e >> 17], 1u);
        unsigned v = e & 0x1FFFFu;
        if (inLds) ebuf[r] = v;
        else       srcs[r0 + r] = (int)v;
    }
    __syncthreads();
    if (inLds) {
        // insertion-sort each dst segment (thread t owns dsts 2t, 2t+1)
        unsigned s0 = tb, s1 = tb + h0;
#pragma unroll
        for (int seg = 0; seg < 2; ++seg) {
            unsigned s = seg ? s1 : s0;
            unsigned len = seg ? h1 : h0;
            for (unsigned a = 1; a < len; ++a) {
                unsigned v = ebuf[s + a];
                unsigned b = a;
                while (b > 0 && ebuf[s + b - 1] > v) {
                    ebuf[s + b] = ebuf[s + b - 1];
                    --b;
                }
                ebuf[s + b] = v;
            }
        }
        __syncthreads();
        for (unsigned k = t; k < cnt; k += 256)
            srcs[r0 + k] = (int)ebuf[k];
    }
    if (bb == 0 && t == 0) offs[N] = Etot;
}

// ---------------- weight transpose to fp16: Wt[n*128 + k] = W[k*Nc + n] ----------------

__global__ void transpose_w(const float* __restrict__ W, __half* __restrict__ Wt,
                            int K, int Nc) {
    int idx = blockIdx.x * 256 + threadIdx.x;
    if (idx >= K * Nc) return;
    int n = idx / K, k = idx - n * K;
    Wt[n * K + k] = __float2half(W[k * Nc + n]);
}

// ---------------- MFMA GEMM + fused alphas ----------------
// C[M,NC] = A[M,128] * W[128,NC]; W passed pre-transposed fp16 Wt[NC][128].
// Block = 256 thr = 4 waves; wave computes 16 rows x NC cols, no LDS.

template <int NC, int H, typename InT>
__global__ __launch_bounds__(256) void gemm_mfma(const InT* __restrict__ A,
                                                 const __half* __restrict__ Wt,
                                                 __half* __restrict__ C,
                                                 const float* __restrict__ a_src,
                                                 const float* __restrict__ a_dst,
                                                 float* __restrict__ as,
                                                 float* __restrict__ ad, int M) {
    constexpr int NT = NC / 16;      // col tiles (8 or 4)
    constexpr int TPH = NT / H;      // tiles per head (2 or 4)
    int wave = threadIdx.x >> 6;
    int lane = threadIdx.x & 63;
    int quad = lane >> 4, col = lane & 15;
    int row0 = blockIdx.x * 64 + wave * 16;
    int arow = row0 + col;           // A fragment row (m = lane&15)
    if (arow >= M) arow = M - 1;
    floatx4 acc[NT] = {};
    const __half* wp = Wt + col * 128 + quad * 8;   // + t*16*128 + k0 per step
#pragma unroll
    for (int k0 = 0; k0 < 128; k0 += 32) {
        half8 af;
        if constexpr (sizeof(InT) == 4) {
            const float* ap = (const float*)A + (size_t)arow * 128 + k0 + quad * 8;
            float4 v0 = *reinterpret_cast<const float4*>(ap);
            float4 v1 = *reinterpret_cast<const float4*>(ap + 4);
            af[0] = (_Float16)v0.x; af[1] = (_Float16)v0.y;
            af[2] = (_Float16)v0.z; af[3] = (_Float16)v0.w;
            af[4] = (_Float16)v1.x; af[5] = (_Float16)v1.y;
            af[6] = (_Float16)v1.z; af[7] = (_Float16)v1.w;
        } else {
            af = *reinterpret_cast<const half8*>((const __half*)A + (size_t)arow * 128 + k0 + quad * 8);
        }
#pragma unroll
        for (int t = 0; t < NT; ++t) {
            half8 bf = *reinterpret_cast<const half8*>(wp + t * 16 * 128 + k0);
            acc[t] = __builtin_amdgcn_mfma_f32_16x16x32_f16(af, bf, acc[t], 0, 0, 0);
        }
    }
    // epilogue
    float sa[NT], da[NT];
#pragma unroll
    for (int t = 0; t < NT; ++t) {
        sa[t] = a_src[t * 16 + col];
        da[t] = a_dst[t * 16 + col];
    }
    int rbase = row0 + quad * 4;
#pragma unroll
    for (int reg = 0; reg < 4; ++reg) {
        int row = rbase + reg;
        bool live = row < M;
        if (live) {
#pragma unroll
            for (int t = 0; t < NT; ++t)
                C[(size_t)row * NC + t * 16 + col] = __float2half(acc[t][reg]);
        }
#pragma unroll
        for (int h = 0; h < H; ++h) {
            float ps = 0.f, pd = 0.f;
#pragma unroll
            for (int tt = 0; tt < TPH; ++tt) {
                int t = h * TPH + tt;
                ps = fmaf(acc[t][reg], sa[t], ps);
                pd = fmaf(acc[t][reg], da[t], pd);
            }
#pragma unroll
            for (int o = 1; o < 16; o <<= 1) {
                ps += __shfl_xor(ps, o, 64);
                pd += __shfl_xor(pd, o, 64);
            }
            if (col == 0 && live) {
                as[(size_t)row * H + h] = ps * LOG2E;
                ad[(size_t)row * H + h] = pd * LOG2E;
            }
        }
    }
}

// ---------------- aggregation: 4 dst nodes per wave, 16 lanes per node ----------------

template <int H, int ROWS, int CW, bool DOELU, typename OutT>
__global__ __launch_bounds__(256) void aggregateQ(const __half* __restrict__ h,
                                                  const float* __restrict__ as,
                                                  const float* __restrict__ ad,
                                                  const int* __restrict__ offs,
                                                  const int* __restrict__ srcs,
                                                  const float* __restrict__ bias,
                                                  OutT* __restrict__ out, int N) {
    constexpr int CPL = CW / 16;    // channels per lane (8 or 4)
    constexpr int NH2 = CPL / 2;    // half2 per lane
    unsigned wave = (blockIdx.x * blockDim.x + threadIdx.x) >> 6;
    unsigned lane = threadIdx.x & 63;
    unsigned lig = lane & 15;       // lane in group
    unsigned node = wave * 4u + (lane >> 4);
    bool live = node < (unsigned)N;
    unsigned nc = live ? node : (unsigned)(N - 1);
    unsigned chan = lig * CPL;
    unsigned head = (chan * H) / ROWS;
    float adv = ad[nc * H + head];
    int e0 = offs[nc], e1 = offs[nc + 1];
    int deg = e1 - e0, e1m1 = e1 - 1;
    int md = deg;
    md = max(md, __shfl_xor(md, 16, 64));
    md = max(md, __shfl_xor(md, 32, 64));
    float2 acc[NH2] = {};
    float den = 0.f;
    for (int k = 0; k < md; k += 2) {
        unsigned ja = (unsigned)srcs[min(e0 + k, e1m1)];
        unsigned jb = (unsigned)srcs[min(e0 + k + 1, e1m1)];
        float ta = as[ja * H + head] + adv;
        float tb = as[jb * H + head] + adv;
        __half2 ha[NH2], hb[NH2];
        if constexpr (NH2 == 4) {
            uint4 va = *reinterpret_cast<const uint4*>(h + ja * (unsigned)ROWS + chan);
            uint4 vb = *reinterpret_cast<const uint4*>(h + jb * (unsigned)ROWS + chan);
            memcpy(ha, &va, 16);
            memcpy(hb, &vb, 16);
        } else {
            uint2 va = *reinterpret_cast<const uint2*>(h + ja * (unsigned)ROWS + chan);
            uint2 vb = *reinterpret_cast<const uint2*>(h + jb * (unsigned)ROWS + chan);
            memcpy(ha, &va, 8);
            memcpy(hb, &vb, 8);
        }
        float xa = exp2_fast(fmaxf(ta, 0.2f * ta));
        float xb = exp2_fast(fmaxf(tb, 0.2f * tb));
        xa = (k < deg) ? xa : 0.f;
        xb = (k + 1 < deg) ? xb : 0.f;
#pragma unroll
        for (int q = 0; q < NH2; ++q) {
            float2 fa = __half22float2(ha[q]);
            float2 fb = __half22float2(hb[q]);
            acc[q].x = fmaf(xa, fa.x, acc[q].x);
            acc[q].y = fmaf(xa, fa.y, acc[q].y);
            acc[q].x = fmaf(xb, fb.x, acc[q].x);
            acc[q].y = fmaf(xb, fb.y, acc[q].y);
        }
        den += xa + xb;
    }
    float r = 1.0f / (den + 1e-16f);
    if (!live) return;
    const float* bp = bias + chan;
    if constexpr (sizeof(OutT) == 2) {
        __half2 st[NH2];
#pragma unroll
        for (int q = 0; q < NH2; ++q) {
            float v0 = acc[q].x * r + bp[2 * q];
            float v1 = acc[q].y * r + bp[2 * q + 1];
            if constexpr (DOELU) {
                v0 = (v0 > 0.f) ? v0 : expm1f(v0);
                v1 = (v1 > 0.f) ? v1 : expm1f(v1);
            }
            st[q] = __floats2half2_rn(v0, v1);
        }
        if constexpr (NH2 == 4) {
            uint4 v; memcpy(&v, st, 16);
            *reinterpret_cast<uint4*>((__half*)out + node * (unsigned)ROWS + chan) = v;
        } else {
            uint2 v; memcpy(&v, st, 8);
            *reinterpret_cast<uint2*>((__half*)out + node * (unsigned)ROWS + chan) = v;
        }
    } else {
        float vs[CPL];
#pragma unroll
        for (int q = 0; q < NH2; ++q) {
            float v0 = acc[q].x * r + bp[2 * q];
            float v1 = acc[q].y * r + bp[2 * q + 1];
            if constexpr (DOELU) {
                v0 = (v0 > 0.f) ? v0 : expm1f(v0);
                v1 = (v1 > 0.f) ? v1 : expm1f(v1);
            }
            vs[2 * q] = v0;
            vs[2 * q + 1] = v1;
        }
#pragma unroll
        for (int q4 = 0; q4 < CPL; q4 += 4) {
            float4 v = make_float4(vs[q4], vs[q4 + 1], vs[q4 + 2], vs[q4 + 3]);
            *reinterpret_cast<float4*>((float*)out + node * (unsigned)ROWS + chan + q4) = v;
        }
    }
}

// ---------------- launch ----------------

extern "C" void kernel_launch(void* const* d_in, const int* in_sizes, int n_in,
                              void* d_out, int out_size, void* d_ws, size_t ws_size,
                              hipStream_t stream) {
    const float* x      = (const float*)d_in[0];
    const int*   ei     = (const int*)d_in[1];
    const float* W1     = (const float*)d_in[2];
    const float* a_src1 = (const float*)d_in[3];
    const float* a_dst1 = (const float*)d_in[4];
    const float* b1     = (const float*)d_in[5];
    const float* W2     = (const float*)d_in[6];
    const float* a_src2 = (const float*)d_in[7];
    const float* a_dst2 = (const float*)d_in[8];
    const float* b2     = (const float*)d_in[9];
    float* out = (float*)d_out;

    const int N = out_size / 64;          // 100000
    const int E = in_sizes[1] / 2;        // 1600000
    const int Etot = E + N;

    size_t off = 0;
    auto carve = [&](size_t bytes) -> void* {
        void* p = (char*)d_ws + off;
        off += (bytes + 255) & ~(size_t)255;
        return p;
    };
    __half* h1      = (__half*)carve((size_t)N * 128 * 2);   // fp16 h, layer 1
    __half* hmid    = (__half*)carve((size_t)N * 128 * 2);   // fp16 ELU output
    float* as1      = (float*)carve((size_t)N * 4 * 4);
    float* ad1      = (float*)carve((size_t)N * 4 * 4);
    float* as2      = (float*)carve((size_t)N * 4);
    float* ad2      = (float*)carve((size_t)N * 4);
    int*   offs     = (int*)carve((size_t)(N + 1) * 4);
    int*   srcs     = (int*)carve((size_t)Etot * 4);
    unsigned* rec   = (unsigned*)carve((size_t)Etot * 4);
    unsigned* bcount  = (unsigned*)carve(NBK * 4);
    unsigned* bbase   = (unsigned*)carve((NBK + 1) * 4);
    unsigned* bcursor = (unsigned*)carve(NBK * 4);
    __half* Wt1h    = (__half*)carve(128 * 128 * 2);
    __half* Wt2h    = (__half*)carve(64 * 128 * 2);
    __half* h2      = h1;    // alias: h1 dead after aggregate1

    // CSR build via bucketed counting sort (shared by both layers)
    hipMemsetAsync(bcount, 0, NBK * sizeof(unsigned), stream);
    bucket_hist<<<128, 256, 0, stream>>>(ei, E, N, bcount);
    scan_buckets<<<1, 256, 0, stream>>>(bcount, bbase, bcursor);
    bucket_scatter<<<(Etot + CH1 - 1) / CH1, 256, 0, stream>>>(ei, E, N, bcursor, rec);
    bucket_sort<<<(N + DPB - 1) / DPB, 256, 0, stream>>>(rec, bbase, offs, srcs, N, Etot);

    // fp16 transposed weights (tiny, once per launch)
    transpose_w<<<64, 256, 0, stream>>>(W1, Wt1h, 128, 128);
    transpose_w<<<32, 256, 0, stream>>>(W2, Wt2h, 128, 64);

    // Layer 1: MFMA gemm (alphas fused) + single-pass aggregation
    gemm_mfma<128, 4, float><<<(N + 63) / 64, 256, 0, stream>>>(
        x, Wt1h, h1, a_src1, a_dst1, as1, ad1, N);
    aggregateQ<4, 128, 128, true, __half><<<(N + 15) / 16, 256, 0, stream>>>(
        h1, as1, ad1, offs, srcs, b1, hmid, N);

    // Layer 2
    gemm_mfma<64, 1, __half><<<(N + 63) / 64, 256, 0, stream>>>(
        hmid, Wt2h, h2, a_src2, a_dst2, as2, ad2, N);
    aggregateQ<1, 64, 64, false, float><<<(N + 15) / 16, 256, 0, stream>>>(
        h2, as2, ad2, offs, srcs, b2, out, N);
}